// Round 12
// baseline (2819.363 us; speedup 1.0000x reference)
//
#include <hip/hip_runtime.h>

typedef short short8 __attribute__((ext_vector_type(8)));
typedef float f32x4 __attribute__((ext_vector_type(4)));
typedef float f4 __attribute__((ext_vector_type(4)));
typedef unsigned short ushort_t;

#define VOCAB 30000
#define DW 512
#define KDIM 512
#define HDIM 512
#define G3 1536
#define TT 50
#define BB 128
#define M_ROWS 6400   /* T*B */
#define NPAD 30208    /* 236*128 */
#define NT2 472       /* partial tiles: 236 nblocks x 2 wc-waves */

__device__ __forceinline__ float b2f(ushort_t u){ return __uint_as_float(((unsigned)u)<<16); }
__device__ __forceinline__ ushort_t f2b(float f){
    unsigned u = __float_as_uint(f);
    unsigned r = (u + 0x7fffu + ((u>>16)&1u)) >> 16;
    return (ushort_t)r;
}
__device__ __forceinline__ float sigf(float x){
    float e = __expf(-x);
    return __builtin_amdgcn_rcpf(1.0f + e);
}
__device__ __forceinline__ float tanh_(float x){
    return 2.0f*sigf(2.0f*x) - 1.0f;   // safe at +-inf
}
__device__ __forceinline__ void gload16(const ushort_t* g, char* l){
    __builtin_amdgcn_global_load_lds((const __attribute__((address_space(1))) void*)g,
                                     (__attribute__((address_space(3))) void*)l, 16, 0, 0);
}

// ---------- setup: W_out convert + pad-zero (grid exact: NPAD*DW/4/256) ----------
__global__ void k_cvtW(const f4* __restrict__ s, ushort_t* __restrict__ d){
    int i = blockIdx.x*blockDim.x + threadIdx.x;     // < NPAD*DW/4
    uint2 o = make_uint2(0u, 0u);
    if (i < VOCAB*DW/4){
        f4 v = s[i];
        o.x = (unsigned)f2b(v[0]) | ((unsigned)f2b(v[1]) << 16);
        o.y = (unsigned)f2b(v[2]) | ((unsigned)f2b(v[3]) << 16);
    }
    *(uint2*)(d + (size_t)i*4) = o;
}
// ---------- setup: Wih+Whh convert, biasg, h_b init, done-counter zero ----------
__global__ void k_small(const f4* __restrict__ wih, const f4* __restrict__ whh,
                        ushort_t* __restrict__ dih, ushort_t* __restrict__ dhh,
                        const float* __restrict__ bi, const float* __restrict__ bh,
                        float* __restrict__ bg, ushort_t* __restrict__ hb,
                        int* __restrict__ done){
    int i = blockIdx.x*blockDim.x + threadIdx.x;     // < G3*DW/4
    {
        f4 v = wih[i];
        unsigned lo = (unsigned)f2b(v[0]) | ((unsigned)f2b(v[1]) << 16);
        unsigned hi = (unsigned)f2b(v[2]) | ((unsigned)f2b(v[3]) << 16);
        *(uint2*)(dih + (size_t)i*4) = make_uint2(lo, hi);
        v = whh[i];
        lo = (unsigned)f2b(v[0]) | ((unsigned)f2b(v[1]) << 16);
        hi = (unsigned)f2b(v[2]) | ((unsigned)f2b(v[3]) << 16);
        *(uint2*)(dhh + (size_t)i*4) = make_uint2(lo, hi);
    }
    if (i < G3) bg[i] = bi[i] + (i < 2*HDIM ? bh[i] : 0.0f);
    if (i < BB*HDIM) hb[i] = 0;                      // buffer 0 only (buffer 1 written before read)
    if (i < TT*8) done[i] = 0;                       // re-zeroed every call (replay-safe)
}
__global__ void k_gather(const float* __restrict__ emb, const int* __restrict__ idx,
                         ushort_t* __restrict__ x){
    int row = blockIdx.x;
    int v = idx[row];
    const float2* src = (const float2*)(emb + (size_t)v*DW);
    unsigned* dst = (unsigned*)(x + (size_t)row*DW);
    for (int d = threadIdx.x; d < DW/2; d += blockDim.x){
        float2 w = src[d];
        dst[d] = (unsigned)f2b(w.x) | ((unsigned)f2b(w.y) << 16);
    }
}

// ---------- phase A: 128x128 m97-structure bf16 GEMM (BK=32, r8-verified) ----------
template<int NBLK>
__global__ __launch_bounds__(256, 3) void k_gemmA(const ushort_t* __restrict__ A,
        const ushort_t* __restrict__ Bw, const float* __restrict__ bias,
        ushort_t* __restrict__ Cout){
    __shared__ ushort_t As[128*32];
    __shared__ ushort_t Bs[128*32];
    const int nwg = NBLK * 50;
    const int q = nwg >> 3;
    int wgid = (blockIdx.x & 7)*q + (blockIdx.x >> 3);
    int band = wgid / (10*NBLK);
    int rr   = wgid % (10*NBLK);
    int nb = rr / 10;
    int mb = band*10 + (rr % 10);
    int n0 = nb*128, m0 = mb*128;

    int lane = threadIdx.x & 63, wv = threadIdx.x >> 6;
    int lo = lane & 15, hi = lane >> 4;
    int wr = wv >> 1, wc = wv & 1;
    f32x4 acc[4][4] = {};
    int xsl = ((lane & 3) ^ ((lane >> 3) & 3)) * 8;
    const ushort_t* gA = A  + (size_t)(m0 + wv*32 + (lane>>2))*KDIM + xsl;
    const ushort_t* gB = Bw + (size_t)(n0 + wv*32 + (lane>>2))*KDIM + xsl;
    char* lA = (char*)As + wv*2048;
    char* lB = (char*)Bs + wv*2048;
    int rchunk = (hi ^ ((lo >> 1) & 3)) * 8;
    for (int kt = 0; kt < 16; ++kt){
        __syncthreads();
        int k0 = kt*32;
        gload16(gA + k0,           lA);
        gload16(gA + 16*KDIM + k0, lA + 1024);
        gload16(gB + k0,           lB);
        gload16(gB + 16*KDIM + k0, lB + 1024);
        __syncthreads();
        short8 av[4], bv[4];
        #pragma unroll
        for (int mi = 0; mi < 4; ++mi)
            av[mi] = *(const short8*)&As[(wr*64 + mi*16 + lo)*32 + rchunk];
        #pragma unroll
        for (int ni = 0; ni < 4; ++ni)
            bv[ni] = *(const short8*)&Bs[(wc*64 + ni*16 + lo)*32 + rchunk];
        #pragma unroll
        for (int mi = 0; mi < 4; ++mi)
            #pragma unroll
            for (int ni = 0; ni < 4; ++ni)
                acc[mi][ni] = __builtin_amdgcn_mfma_f32_16x16x32_bf16(av[mi], bv[ni], acc[mi][ni], 0, 0, 0);
    }
    #pragma unroll
    for (int ni = 0; ni < 4; ++ni){
        int n = n0 + wc*64 + ni*16 + lo;
        float bb = bias[n];
        #pragma unroll
        for (int mi = 0; mi < 4; ++mi){
            #pragma unroll
            for (int j = 0; j < 4; ++j){
                int m = m0 + wr*64 + mi*16 + hi*4 + j;
                Cout[(size_t)m*G3 + n] = f2b(acc[mi][ni][j] + bb);
            }
        }
    }
}

// ---------- persistent GRU scan: 256 WGs (32 ctiles x 8 btiles), 50 steps in-kernel ----------
// Sync is per-(step,btile): h rows of btile are produced/consumed ONLY by its own
// 32 ctile-WGs -> counter done[t*8+btile] (release-fence + atomicAdd / acquire-spin,
// the r5-proven-correct pattern, now at full-chip occupancy).
// Whh slice (48 KB) in LDS once; h_f cell lives in a REGISTER (1 per thread);
// only bf16 h_b crosses WGs. Split-K x4 across waves (r9-verified), LDS combine.
__global__ __launch_bounds__(256) void k_scan2(const ushort_t* __restrict__ Whh,
        const float* __restrict__ bh, const ushort_t* __restrict__ xg,
        ushort_t* __restrict__ h_b, ushort_t* __restrict__ outs,
        int* __restrict__ done){
    __shared__ short8 Bl[3*16*4*16];        // 48 KiB [g][kk][hi][lo]
    __shared__ float gl[3][4][16][17];      // 13.3 KiB split-K partials
    int tid = threadIdx.x;
    int lane = tid & 63, wv = tid >> 6;
    int lo = lane & 15, hi = lane >> 4;
    int ctile = blockIdx.x & 31, btile = blockIdx.x >> 5;
    int c16 = ctile * 16, b0 = btile * 16;
    // load Whh slice -> LDS (same layout as r5-verified k_scan)
    for (int idx = tid; idx < 3072; idx += 256){
        int g = idx >> 10, rem = idx & 1023;
        int kk = rem >> 6, h4 = (rem >> 4) & 3, l = rem & 15;
        Bl[idx] = *(const short8*)(Whh + (size_t)(g*HDIM + c16 + l)*HDIM + kk*32 + h4*8);
    }
    int b = tid >> 4, c = tid & 15;         // this thread's owned cell
    int bt = b0 + b, cc = c16 + c;
    float bhn = bh[2*HDIM + cc];
    float hold = 0.0f;                      // register-resident h_f cell
    __syncthreads();
    int cur = 0;
    for (int t = 0; t < TT; ++t){
        if (t > 0){
            if (tid == 0){
                while (__hip_atomic_load(&done[(t-1)*8 + btile], __ATOMIC_ACQUIRE,
                                         __HIP_MEMORY_SCOPE_AGENT) < 32)
                    __builtin_amdgcn_s_sleep(2);
            }
            __syncthreads();
            __threadfence();                // acquire: see producers' h_b stores
        }
        // split-K x4: wave wv covers kk in [wv*4, wv*4+4)
        f32x4 acc[3] = {};
        const ushort_t* hrow = h_b + (size_t)cur*BB*HDIM + (size_t)(b0 + lo)*HDIM;
        #pragma unroll
        for (int i = 0; i < 4; ++i){
            int kk = wv*4 + i;
            short8 a = *(const short8*)(hrow + kk*32 + hi*8);
            #pragma unroll
            for (int g = 0; g < 3; ++g)
                acc[g] = __builtin_amdgcn_mfma_f32_16x16x32_bf16(
                             a, Bl[((g*16 + kk)*4 + hi)*16 + lo], acc[g], 0, 0, 0);
        }
        #pragma unroll
        for (int g = 0; g < 3; ++g)
            #pragma unroll
            for (int j = 0; j < 4; ++j)
                gl[g][wv][hi*4 + j][lo] = acc[g][j];
        __syncthreads();
        float hr = gl[0][0][b][c] + gl[0][1][b][c] + gl[0][2][b][c] + gl[0][3][b][c];
        float hz = gl[1][0][b][c] + gl[1][1][b][c] + gl[1][2][b][c] + gl[1][3][b][c];
        float hn = gl[2][0][b][c] + gl[2][1][b][c] + gl[2][2][b][c] + gl[2][3][b][c];
        const ushort_t* xgt = xg + (size_t)t*BB*G3 + (size_t)bt*G3;
        float xr = b2f(xgt[cc]);
        float xz = b2f(xgt[HDIM + cc]);
        float xn = b2f(xgt[2*HDIM + cc]);
        float r  = sigf(hr + xr);
        float z  = sigf(hz + xz);
        float n  = tanh_(xn + r*(hn + bhn));
        float hnew = (1.0f - z)*n + z*hold;
        hold = hnew;
        ushort_t hv = f2b(hnew);
        int nxt = cur ^ 1;
        h_b[(size_t)nxt*BB*HDIM + (size_t)bt*HDIM + cc] = hv;
        outs[((size_t)t*BB + bt)*HDIM + cc] = hv;
        __threadfence();                    // release: h_b visible device-wide
        __syncthreads();                    // all 256 threads' stores fenced
        if (tid == 0) atomicAdd(&done[t*8 + btile], 1);
        cur = nxt;
    }
}

// ---------- phase C: 128x128 BK=64 bf16 GEMM + sumexp epilogue (r11-verified) ----------
template<int NBLK>
__global__ __launch_bounds__(256, 4) void k_gemmC(const ushort_t* __restrict__ A,
        const ushort_t* __restrict__ Bw, const float* __restrict__ bo,
        float* __restrict__ psum){
    __shared__ ushort_t As[128*64];
    __shared__ ushort_t Bs[128*64];
    const int nwg = NBLK * 50;
    const int q = nwg >> 3;
    int wgid = (blockIdx.x & 7)*q + (blockIdx.x >> 3);
    int band = wgid / (10*NBLK);
    int rr   = wgid % (10*NBLK);
    int nb = rr / 10;
    int mb = band*10 + (rr % 10);
    int n0 = nb*128, m0 = mb*128;

    int tid = threadIdx.x;
    int lane = tid & 63, wv = tid >> 6;
    int lo = lane & 15, hi = lane >> 4;
    int wr = wv >> 1, wc = wv & 1;
    f32x4 acc[4][4] = {};
    int srow = lane >> 3;
    int xslot = (lane & 7) ^ srow;
    const ushort_t* gA = A  + (size_t)(m0 + wv*32 + srow)*KDIM + xslot*8;
    const ushort_t* gB = Bw + (size_t)(n0 + wv*32 + srow)*KDIM + xslot*8;
    char* lA = (char*)As + (size_t)(wv*32)*128;
    char* lB = (char*)Bs + (size_t)(wv*32)*128;
    for (int kt = 0; kt < 8; ++kt){
        __syncthreads();
        int k0 = kt*64;
        #pragma unroll
        for (int c4 = 0; c4 < 4; ++c4){
            gload16(gA + (size_t)c4*8*KDIM + k0, lA + c4*8*128);
            gload16(gB + (size_t)c4*8*KDIM + k0, lB + c4*8*128);
        }
        __syncthreads();
        short8 av[4][2], bv[4][2];
        #pragma unroll
        for (int mi = 0; mi < 4; ++mi){
            int rrow = wr*64 + mi*16 + lo;
            #pragma unroll
            for (int ks = 0; ks < 2; ++ks)
                av[mi][ks] = *(const short8*)&As[rrow*64 + (((ks*4+hi) ^ (lo&7)))*8];
        }
        #pragma unroll
        for (int ni = 0; ni < 4; ++ni){
            int rrow = wc*64 + ni*16 + lo;
            #pragma unroll
            for (int ks = 0; ks < 2; ++ks)
                bv[ni][ks] = *(const short8*)&Bs[rrow*64 + (((ks*4+hi) ^ (lo&7)))*8];
        }
        #pragma unroll
        for (int mi = 0; mi < 4; ++mi)
            #pragma unroll
            for (int ni = 0; ni < 4; ++ni){
                acc[mi][ni] = __builtin_amdgcn_mfma_f32_16x16x32_bf16(av[mi][0], bv[ni][0], acc[mi][ni], 0, 0, 0);
                acc[mi][ni] = __builtin_amdgcn_mfma_f32_16x16x32_bf16(av[mi][1], bv[ni][1], acc[mi][ni], 0, 0, 0);
            }
    }
    float bov[4];
    bool valid[4];
    #pragma unroll
    for (int ni = 0; ni < 4; ++ni){
        int col = n0 + wc*64 + ni*16 + lo;
        valid[ni] = (col < VOCAB);
        bov[ni] = valid[ni] ? bo[col] : 0.0f;
    }
    int tile = nb*2 + wc;
    #pragma unroll
    for (int mi = 0; mi < 4; ++mi){
        #pragma unroll
        for (int j = 0; j < 4; ++j){
            float s = 0.0f;
            #pragma unroll
            for (int ni = 0; ni < 4; ++ni)
                s += valid[ni] ? __expf(acc[mi][ni][j] + bov[ni]) : 0.0f;
            for (int d = 1; d < 16; d <<= 1) s += __shfl_xor(s, d, 64);
            if (lo == 0){
                int m = m0 + wr*64 + mi*16 + hi*4 + j;
                psum[(size_t)m*NT2 + tile] = s;
            }
        }
    }
}

// ---------- fused: lse combine + nll per row (wave per row) ----------
__global__ __launch_bounds__(256) void k_loss(const ushort_t* __restrict__ outs,
        const ushort_t* __restrict__ Wo, const float* __restrict__ bo,
        const float* __restrict__ psum, const int* __restrict__ tgt,
        float* __restrict__ out){
    int lane = threadIdx.x & 63, wv = threadIdx.x >> 6;
    int row = blockIdx.x*4 + wv;
    int tg = tgt[row];
    const float* ps = psum + (size_t)row*NT2;
    float S = 0.0f;
    for (int t = lane; t < NT2; t += 64) S += ps[t];
    for (int d = 1; d < 64; d <<= 1) S += __shfl_xor(S, d, 64);
    float lse = __logf(S);
    const ushort_t* a = outs + (size_t)row*HDIM + lane*8;
    const ushort_t* w = Wo + (size_t)tg*DW + lane*8;
    float s = 0.0f;
    #pragma unroll
    for (int j = 0; j < 8; ++j) s += b2f(a[j]) * b2f(w[j]);
    for (int d = 1; d < 64; d <<= 1) s += __shfl_xor(s, d, 64);
    if (lane == 0){
        float logit = s + bo[tg];
        out[row] = (tg != 0) ? (lse - logit) : 0.0f;
    }
}

// ---------- obj = sum(loss)/max(count,1) ----------
__global__ __launch_bounds__(1024) void k_obj(const float* __restrict__ loss,
        const int* __restrict__ tgt, float* __restrict__ out){
    __shared__ float ss[1024];
    __shared__ int   sc[1024];
    float s = 0.0f; int c = 0;
    for (int i = threadIdx.x; i < M_ROWS; i += 1024){
        s += loss[i];
        c += (tgt[i] != 0) ? 1 : 0;
    }
    ss[threadIdx.x] = s; sc[threadIdx.x] = c;
    __syncthreads();
    for (int d = 512; d > 0; d >>= 1){
        if (threadIdx.x < (unsigned)d){ ss[threadIdx.x] += ss[threadIdx.x+d]; sc[threadIdx.x] += sc[threadIdx.x+d]; }
        __syncthreads();
    }
    if (threadIdx.x == 0) out[M_ROWS] = ss[0] / (float)(sc[0] > 0 ? sc[0] : 1);
}

extern "C" void kernel_launch(void* const* d_in, const int* in_sizes, int n_in,
                              void* d_out, int out_size, void* d_ws, size_t ws_size,
                              hipStream_t stream) {
    const int*   review_input  = (const int*)d_in[2];
    const int*   review_target = (const int*)d_in[3];
    const float* word_emb = (const float*)d_in[4];
    const float* W_ih = (const float*)d_in[5];
    const float* W_hh = (const float*)d_in[6];
    const float* b_ih = (const float*)d_in[7];
    const float* b_hh = (const float*)d_in[8];
    const float* W_out = (const float*)d_in[9];
    const float* b_out = (const float*)d_in[10];
    float* out = (float*)d_out;
    (void)n_in; (void)in_sizes; (void)out_size; (void)ws_size;

    char* ws = (char*)d_ws;
    size_t off = 0;
    auto alloc = [&](size_t bytes)->char*{
        char* p = ws + off;
        off = (off + bytes + 255) & ~(size_t)255;
        return p;
    };
    ushort_t* Wout_b = (ushort_t*)alloc((size_t)NPAD*DW*2);      // 30.9 MB (padded)
    ushort_t* Wih_b  = (ushort_t*)alloc((size_t)G3*DW*2);
    ushort_t* Whh_b  = (ushort_t*)alloc((size_t)G3*HDIM*2);
    ushort_t* outs_b = (ushort_t*)alloc((size_t)M_ROWS*HDIM*2);  // live through loss
    float*    biasg  = (float*)alloc((size_t)G3*4);
    ushort_t* h_b    = (ushort_t*)alloc((size_t)2*BB*HDIM*2);
    int*      done   = (int*)alloc((size_t)TT*8*4);
    // xb + xg dead by phase C -> psum ([row][tile], 12.1 MB) aliases this span
    ushort_t* xb     = (ushort_t*)alloc((size_t)M_ROWS*DW*2);
    ushort_t* xg     = (ushort_t*)alloc((size_t)M_ROWS*G3*2);
    float*    psum   = (float*)xb;

    // setup: 3 launches
    k_cvtW<<<NPAD*DW/4/256, 256, 0, stream>>>((const f4*)W_out, Wout_b);
    k_small<<<G3*DW/4/256, 256, 0, stream>>>((const f4*)W_ih, (const f4*)W_hh,
                                             Wih_b, Whh_b, b_ih, b_hh, biasg, h_b, done);
    k_gather<<<M_ROWS, 256, 0, stream>>>(word_emb, review_input, xb);

    // phase A: xg = x @ W_ih^T + biasg   (12 nb x 50 mb = 600 WGs)
    k_gemmA<12><<<600, 256, 0, stream>>>(xb, Wih_b, biasg, xg);

    // phase B: one persistent dispatch, per-btile producer/consumer sync
    k_scan2<<<256, 256, 0, stream>>>(Whh_b, b_hh, xg, h_b, outs_b, done);

    // phase C: fused logits + sumexp partials (236 nb x 50 mb = 11800 WGs), loss, obj
    k_gemmC<236><<<11800, 256, 0, stream>>>(outs_b, Wout_b, b_out, psum);
    k_loss<<<M_ROWS/4, 256, 0, stream>>>(outs_b, Wout_b, b_out, psum, review_target, out);
    k_obj<<<1, 1024, 0, stream>>>(out, review_target, out);
}

// Round 13
// 488.902 us; speedup vs baseline: 5.7667x; 5.7667x over previous
//
#include <hip/hip_runtime.h>

typedef short short8 __attribute__((ext_vector_type(8)));
typedef float f32x4 __attribute__((ext_vector_type(4)));
typedef float f4 __attribute__((ext_vector_type(4)));
typedef unsigned short ushort_t;

#define VOCAB 30000
#define DW 512
#define KDIM 512
#define HDIM 512
#define G3 1536
#define TT 50
#define BB 128
#define M_ROWS 6400   /* T*B */
#define NPAD 30208    /* 236*128 */
#define NT2 472       /* partial tiles: 236 nblocks x 2 wc-waves */

__device__ __forceinline__ float b2f(ushort_t u){ return __uint_as_float(((unsigned)u)<<16); }
__device__ __forceinline__ ushort_t f2b(float f){
    unsigned u = __float_as_uint(f);
    unsigned r = (u + 0x7fffu + ((u>>16)&1u)) >> 16;
    return (ushort_t)r;
}
__device__ __forceinline__ float sigf(float x){
    float e = __expf(-x);
    return __builtin_amdgcn_rcpf(1.0f + e);
}
__device__ __forceinline__ float tanh_(float x){
    return 2.0f*sigf(2.0f*x) - 1.0f;   // safe at +-inf
}
__device__ __forceinline__ void gload16(const ushort_t* g, char* l){
    __builtin_amdgcn_global_load_lds((const __attribute__((address_space(1))) void*)g,
                                     (__attribute__((address_space(3))) void*)l, 16, 0, 0);
}

// ---------- setup: W_out convert+pad; first 768 blocks also do Wih/Whh/biasg/h-init ----------
// grid exact: NPAD*DW/4/256 = 15104 blocks
__global__ void k_setup(const f4* __restrict__ s, ushort_t* __restrict__ d,
                        const f4* __restrict__ wih, const f4* __restrict__ whh,
                        ushort_t* __restrict__ dih, ushort_t* __restrict__ dhh,
                        const float* __restrict__ bi, const float* __restrict__ bh,
                        float* __restrict__ bg, float* __restrict__ hf,
                        ushort_t* __restrict__ hb){
    int i = blockIdx.x*blockDim.x + threadIdx.x;     // < NPAD*DW/4
    uint2 o = make_uint2(0u, 0u);
    if (i < VOCAB*DW/4){
        f4 v = s[i];
        o.x = (unsigned)f2b(v[0]) | ((unsigned)f2b(v[1]) << 16);
        o.y = (unsigned)f2b(v[2]) | ((unsigned)f2b(v[3]) << 16);
    }
    *(uint2*)(d + (size_t)i*4) = o;
    if (i < G3*DW/4){
        f4 v = wih[i];
        unsigned lo = (unsigned)f2b(v[0]) | ((unsigned)f2b(v[1]) << 16);
        unsigned hi = (unsigned)f2b(v[2]) | ((unsigned)f2b(v[3]) << 16);
        *(uint2*)(dih + (size_t)i*4) = make_uint2(lo, hi);
        v = whh[i];
        lo = (unsigned)f2b(v[0]) | ((unsigned)f2b(v[1]) << 16);
        hi = (unsigned)f2b(v[2]) | ((unsigned)f2b(v[3]) << 16);
        *(uint2*)(dhh + (size_t)i*4) = make_uint2(lo, hi);
        if (i < G3) bg[i] = bi[i] + (i < 2*HDIM ? bh[i] : 0.0f);
        if (i < BB*HDIM){ hf[i] = 0.0f; hb[i] = 0; }
    }
}
__global__ void k_gather(const float* __restrict__ emb, const int* __restrict__ idx,
                         ushort_t* __restrict__ x){
    int row = blockIdx.x;
    int v = idx[row];
    const float2* src = (const float2*)(emb + (size_t)v*DW);
    unsigned* dst = (unsigned*)(x + (size_t)row*DW);
    for (int d = threadIdx.x; d < DW/2; d += blockDim.x){
        float2 w = src[d];
        dst[d] = (unsigned)f2b(w.x) | ((unsigned)f2b(w.y) << 16);
    }
}

// ---------- phase A: 128x128 m97-structure bf16 GEMM (BK=32, r8-verified) ----------
template<int NBLK>
__global__ __launch_bounds__(256, 3) void k_gemmA(const ushort_t* __restrict__ A,
        const ushort_t* __restrict__ Bw, const float* __restrict__ bias,
        ushort_t* __restrict__ Cout){
    __shared__ ushort_t As[128*32];
    __shared__ ushort_t Bs[128*32];
    const int nwg = NBLK * 50;
    const int q = nwg >> 3;
    int wgid = (blockIdx.x & 7)*q + (blockIdx.x >> 3);
    int band = wgid / (10*NBLK);
    int rr   = wgid % (10*NBLK);
    int nb = rr / 10;
    int mb = band*10 + (rr % 10);
    int n0 = nb*128, m0 = mb*128;

    int lane = threadIdx.x & 63, wv = threadIdx.x >> 6;
    int lo = lane & 15, hi = lane >> 4;
    int wr = wv >> 1, wc = wv & 1;
    f32x4 acc[4][4] = {};
    int xsl = ((lane & 3) ^ ((lane >> 3) & 3)) * 8;
    const ushort_t* gA = A  + (size_t)(m0 + wv*32 + (lane>>2))*KDIM + xsl;
    const ushort_t* gB = Bw + (size_t)(n0 + wv*32 + (lane>>2))*KDIM + xsl;
    char* lA = (char*)As + wv*2048;
    char* lB = (char*)Bs + wv*2048;
    int rchunk = (hi ^ ((lo >> 1) & 3)) * 8;
    for (int kt = 0; kt < 16; ++kt){
        __syncthreads();
        int k0 = kt*32;
        gload16(gA + k0,           lA);
        gload16(gA + 16*KDIM + k0, lA + 1024);
        gload16(gB + k0,           lB);
        gload16(gB + 16*KDIM + k0, lB + 1024);
        __syncthreads();
        short8 av[4], bv[4];
        #pragma unroll
        for (int mi = 0; mi < 4; ++mi)
            av[mi] = *(const short8*)&As[(wr*64 + mi*16 + lo)*32 + rchunk];
        #pragma unroll
        for (int ni = 0; ni < 4; ++ni)
            bv[ni] = *(const short8*)&Bs[(wc*64 + ni*16 + lo)*32 + rchunk];
        #pragma unroll
        for (int mi = 0; mi < 4; ++mi)
            #pragma unroll
            for (int ni = 0; ni < 4; ++ni)
                acc[mi][ni] = __builtin_amdgcn_mfma_f32_16x16x32_bf16(av[mi], bv[ni], acc[mi][ni], 0, 0, 0);
    }
    #pragma unroll
    for (int ni = 0; ni < 4; ++ni){
        int n = n0 + wc*64 + ni*16 + lo;
        float bb = bias[n];
        #pragma unroll
        for (int mi = 0; mi < 4; ++mi){
            #pragma unroll
            for (int j = 0; j < 4; ++j){
                int m = m0 + wr*64 + mi*16 + hi*4 + j;
                Cout[(size_t)m*G3 + n] = f2b(acc[mi][ni][j] + bb);
            }
        }
    }
}

// ---------- phase C: 128x128 BK=64 bf16 GEMM + sumexp epilogue (r11-verified: 230us) ----------
template<int NBLK>
__global__ __launch_bounds__(256, 4) void k_gemmC(const ushort_t* __restrict__ A,
        const ushort_t* __restrict__ Bw, const float* __restrict__ bo,
        float* __restrict__ psum){
    __shared__ ushort_t As[128*64];
    __shared__ ushort_t Bs[128*64];
    const int nwg = NBLK * 50;
    const int q = nwg >> 3;
    int wgid = (blockIdx.x & 7)*q + (blockIdx.x >> 3);
    int band = wgid / (10*NBLK);
    int rr   = wgid % (10*NBLK);
    int nb = rr / 10;
    int mb = band*10 + (rr % 10);
    int n0 = nb*128, m0 = mb*128;

    int tid = threadIdx.x;
    int lane = tid & 63, wv = tid >> 6;
    int lo = lane & 15, hi = lane >> 4;
    int wr = wv >> 1, wc = wv & 1;
    f32x4 acc[4][4] = {};
    int srow = lane >> 3;
    int xslot = (lane & 7) ^ srow;
    const ushort_t* gA = A  + (size_t)(m0 + wv*32 + srow)*KDIM + xslot*8;
    const ushort_t* gB = Bw + (size_t)(n0 + wv*32 + srow)*KDIM + xslot*8;
    char* lA = (char*)As + (size_t)(wv*32)*128;
    char* lB = (char*)Bs + (size_t)(wv*32)*128;
    for (int kt = 0; kt < 8; ++kt){
        __syncthreads();
        int k0 = kt*64;
        #pragma unroll
        for (int c4 = 0; c4 < 4; ++c4){
            gload16(gA + (size_t)c4*8*KDIM + k0, lA + c4*8*128);
            gload16(gB + (size_t)c4*8*KDIM + k0, lB + c4*8*128);
        }
        __syncthreads();
        short8 av[4][2], bv[4][2];
        #pragma unroll
        for (int mi = 0; mi < 4; ++mi){
            int rrow = wr*64 + mi*16 + lo;
            #pragma unroll
            for (int ks = 0; ks < 2; ++ks)
                av[mi][ks] = *(const short8*)&As[rrow*64 + (((ks*4+hi) ^ (lo&7)))*8];
        }
        #pragma unroll
        for (int ni = 0; ni < 4; ++ni){
            int rrow = wc*64 + ni*16 + lo;
            #pragma unroll
            for (int ks = 0; ks < 2; ++ks)
                bv[ni][ks] = *(const short8*)&Bs[rrow*64 + (((ks*4+hi) ^ (lo&7)))*8];
        }
        #pragma unroll
        for (int mi = 0; mi < 4; ++mi)
            #pragma unroll
            for (int ni = 0; ni < 4; ++ni){
                acc[mi][ni] = __builtin_amdgcn_mfma_f32_16x16x32_bf16(av[mi][0], bv[ni][0], acc[mi][ni], 0, 0, 0);
                acc[mi][ni] = __builtin_amdgcn_mfma_f32_16x16x32_bf16(av[mi][1], bv[ni][1], acc[mi][ni], 0, 0, 0);
            }
    }
    float bov[4];
    bool valid[4];
    #pragma unroll
    for (int ni = 0; ni < 4; ++ni){
        int col = n0 + wc*64 + ni*16 + lo;
        valid[ni] = (col < VOCAB);
        bov[ni] = valid[ni] ? bo[col] : 0.0f;
    }
    int tile = nb*2 + wc;
    #pragma unroll
    for (int mi = 0; mi < 4; ++mi){
        #pragma unroll
        for (int j = 0; j < 4; ++j){
            float s = 0.0f;
            #pragma unroll
            for (int ni = 0; ni < 4; ++ni)
                s += valid[ni] ? __expf(acc[mi][ni][j] + bov[ni]) : 0.0f;
            for (int d = 1; d < 16; d <<= 1) s += __shfl_xor(s, d, 64);
            if (lo == 0){
                int m = m0 + wr*64 + mi*16 + hi*4 + j;
                psum[(size_t)m*NT2 + tile] = s;
            }
        }
    }
}

// ---------- one GRU step, split-K x4 (r8/r11-verified): grid (32,8), block 256 ----------
__global__ __launch_bounds__(256) void k_step(const ushort_t* __restrict__ hprev_b,
        const float* __restrict__ hprev_f, const ushort_t* __restrict__ Whh,
        const ushort_t* __restrict__ xg, const float* __restrict__ bh,
        float* __restrict__ hnext_f, ushort_t* __restrict__ hnext_b,
        ushort_t* __restrict__ outs, int t){
    __shared__ float gl[3][4][16][17];
    int tid = threadIdx.x;
    int lane = tid & 63, wv = tid >> 6;
    int lo = lane & 15, hi = lane >> 4;
    int c16 = blockIdx.x * 16;   // h-col base
    int b0  = blockIdx.y * 16;   // batch base
    f32x4 acc[3] = {};
    const ushort_t* Arow = hprev_b + (size_t)(b0 + lo)*HDIM + wv*128;
    const ushort_t* Bbase = Whh + (size_t)(c16 + lo)*HDIM + wv*128;
    #pragma unroll
    for (int kk = 0; kk < 4; ++kk){
        int k0 = kk*32 + hi*8;
        short8 a = *(const short8*)(Arow + k0);
        #pragma unroll
        for (int g = 0; g < 3; ++g){
            short8 b = *(const short8*)(Bbase + (size_t)g*HDIM*HDIM + k0);
            acc[g] = __builtin_amdgcn_mfma_f32_16x16x32_bf16(a, b, acc[g], 0, 0, 0);
        }
    }
    #pragma unroll
    for (int g = 0; g < 3; ++g)
        #pragma unroll
        for (int j = 0; j < 4; ++j)
            gl[g][wv][hi*4 + j][lo] = acc[g][j];
    __syncthreads();
    int b = tid >> 4, c = tid & 15;
    int bt = b0 + b, cc = c16 + c;
    float hr = gl[0][0][b][c] + gl[0][1][b][c] + gl[0][2][b][c] + gl[0][3][b][c];
    float hz = gl[1][0][b][c] + gl[1][1][b][c] + gl[1][2][b][c] + gl[1][3][b][c];
    float hn = gl[2][0][b][c] + gl[2][1][b][c] + gl[2][2][b][c] + gl[2][3][b][c];
    const ushort_t* xgt = xg + (size_t)t*BB*G3 + (size_t)bt*G3;
    float xr = b2f(xgt[cc]);
    float xz = b2f(xgt[HDIM + cc]);
    float xn = b2f(xgt[2*HDIM + cc]);
    float r  = sigf(hr + xr);
    float z  = sigf(hz + xz);
    float n  = tanh_(xn + r*(hn + bh[2*HDIM + cc]));
    float hold = hprev_f[(size_t)bt*HDIM + cc];
    float hnew = (1.0f - z)*n + z*hold;
    hnext_f[(size_t)bt*HDIM + cc] = hnew;
    ushort_t hv = f2b(hnew);
    hnext_b[(size_t)bt*HDIM + cc] = hv;
    outs[((size_t)t*BB + bt)*HDIM + cc] = hv;
}

// ---------- fused: lse combine + nll per row (wave per row) ----------
__global__ __launch_bounds__(256) void k_loss(const ushort_t* __restrict__ outs,
        const ushort_t* __restrict__ Wo, const float* __restrict__ bo,
        const float* __restrict__ psum, const int* __restrict__ tgt,
        float* __restrict__ out){
    int lane = threadIdx.x & 63, wv = threadIdx.x >> 6;
    int row = blockIdx.x*4 + wv;
    int tg = tgt[row];
    const float* ps = psum + (size_t)row*NT2;
    float S = 0.0f;
    for (int t = lane; t < NT2; t += 64) S += ps[t];
    for (int d = 1; d < 64; d <<= 1) S += __shfl_xor(S, d, 64);
    float lse = __logf(S);
    const ushort_t* a = outs + (size_t)row*HDIM + lane*8;
    const ushort_t* w = Wo + (size_t)tg*DW + lane*8;
    float s = 0.0f;
    #pragma unroll
    for (int j = 0; j < 8; ++j) s += b2f(a[j]) * b2f(w[j]);
    for (int d = 1; d < 64; d <<= 1) s += __shfl_xor(s, d, 64);
    if (lane == 0){
        float logit = s + bo[tg];
        out[row] = (tg != 0) ? (lse - logit) : 0.0f;
    }
}

// ---------- obj = sum(loss)/max(count,1) ----------
__global__ __launch_bounds__(1024) void k_obj(const float* __restrict__ loss,
        const int* __restrict__ tgt, float* __restrict__ out){
    __shared__ float ss[1024];
    __shared__ int   sc[1024];
    float s = 0.0f; int c = 0;
    for (int i = threadIdx.x; i < M_ROWS; i += 1024){
        s += loss[i];
        c += (tgt[i] != 0) ? 1 : 0;
    }
    ss[threadIdx.x] = s; sc[threadIdx.x] = c;
    __syncthreads();
    for (int d = 512; d > 0; d >>= 1){
        if (threadIdx.x < (unsigned)d){ ss[threadIdx.x] += ss[threadIdx.x+d]; sc[threadIdx.x] += sc[threadIdx.x+d]; }
        __syncthreads();
    }
    if (threadIdx.x == 0) out[M_ROWS] = ss[0] / (float)(sc[0] > 0 ? sc[0] : 1);
}

extern "C" void kernel_launch(void* const* d_in, const int* in_sizes, int n_in,
                              void* d_out, int out_size, void* d_ws, size_t ws_size,
                              hipStream_t stream) {
    const int*   review_input  = (const int*)d_in[2];
    const int*   review_target = (const int*)d_in[3];
    const float* word_emb = (const float*)d_in[4];
    const float* W_ih = (const float*)d_in[5];
    const float* W_hh = (const float*)d_in[6];
    const float* b_ih = (const float*)d_in[7];
    const float* b_hh = (const float*)d_in[8];
    const float* W_out = (const float*)d_in[9];
    const float* b_out = (const float*)d_in[10];
    float* out = (float*)d_out;
    (void)n_in; (void)in_sizes; (void)out_size; (void)ws_size;

    char* ws = (char*)d_ws;
    size_t off = 0;
    auto alloc = [&](size_t bytes)->char*{
        char* p = ws + off;
        off = (off + bytes + 255) & ~(size_t)255;
        return p;
    };
    ushort_t* Wout_b = (ushort_t*)alloc((size_t)NPAD*DW*2);      // 30.9 MB (padded)
    ushort_t* Wih_b  = (ushort_t*)alloc((size_t)G3*DW*2);
    ushort_t* Whh_b  = (ushort_t*)alloc((size_t)G3*HDIM*2);
    ushort_t* outs_b = (ushort_t*)alloc((size_t)M_ROWS*HDIM*2);  // live through loss
    float*    biasg  = (float*)alloc((size_t)G3*4);
    float*    h_f    = (float*)alloc((size_t)2*BB*HDIM*4);
    ushort_t* h_b    = (ushort_t*)alloc((size_t)2*BB*HDIM*2);
    // xb + xg dead by phase C -> psum ([row][tile], 12.1 MB) aliases this span
    ushort_t* xb     = (ushort_t*)alloc((size_t)M_ROWS*DW*2);
    ushort_t* xg     = (ushort_t*)alloc((size_t)M_ROWS*G3*2);
    float*    psum   = (float*)xb;

    // setup: 2 launches
    k_setup<<<NPAD*DW/4/256, 256, 0, stream>>>((const f4*)W_out, Wout_b,
                                               (const f4*)W_ih, (const f4*)W_hh,
                                               Wih_b, Whh_b, b_ih, b_hh, biasg, h_f, h_b);
    k_gather<<<M_ROWS, 256, 0, stream>>>(word_emb, review_input, xb);

    // phase A: xg = x @ W_ih^T + biasg   (12 nb x 50 mb = 600 WGs)
    k_gemmA<12><<<600, 256, 0, stream>>>(xb, Wih_b, biasg, xg);

    // phase B: 50 sequential steps, double-buffered h (dependent launches = the
    // measured-cheapest scan mechanism on CDNA4; r5/r10/r12 alternatives 5-25x worse)
    for (int t = 0; t < TT; ++t){
        int cur = t & 1, nxt = cur ^ 1;
        k_step<<<dim3(HDIM/16, BB/16), 256, 0, stream>>>(h_b + (size_t)cur*BB*HDIM,
                                       h_f + (size_t)cur*BB*HDIM,
                                       Whh_b, xg, b_hh,
                                       h_f + (size_t)nxt*BB*HDIM,
                                       h_b + (size_t)nxt*BB*HDIM,
                                       outs_b, t);
    }

    // phase C: fused logits + sumexp partials (236 nb x 50 mb = 11800 WGs), loss, obj
    k_gemmC<236><<<11800, 256, 0, stream>>>(outs_b, Wout_b, b_out, psum);
    k_loss<<<M_ROWS/4, 256, 0, stream>>>(outs_b, Wout_b, b_out, psum, review_target, out);
    k_obj<<<1, 1024, 0, stream>>>(out, review_target, out);
}

// Round 14
// 483.475 us; speedup vs baseline: 5.8315x; 1.0112x over previous
//
#include <hip/hip_runtime.h>

typedef short short8 __attribute__((ext_vector_type(8)));
typedef float f32x4 __attribute__((ext_vector_type(4)));
typedef float f4 __attribute__((ext_vector_type(4)));
typedef unsigned short ushort_t;

#define VOCAB 30000
#define DW 512
#define KDIM 512
#define HDIM 512
#define G3 1536
#define TT 50
#define BB 128
#define M_ROWS 6400   /* T*B */
#define NPAD 30208    /* 236*128 */
#define NT2 472       /* partial tiles: 236 nblocks x 2 wc-waves */

__device__ __forceinline__ float b2f(ushort_t u){ return __uint_as_float(((unsigned)u)<<16); }
__device__ __forceinline__ ushort_t f2b(float f){
    unsigned u = __float_as_uint(f);
    unsigned r = (u + 0x7fffu + ((u>>16)&1u)) >> 16;
    return (ushort_t)r;
}
__device__ __forceinline__ float sigf(float x){
    float e = __expf(-x);
    return __builtin_amdgcn_rcpf(1.0f + e);
}
__device__ __forceinline__ float tanh_(float x){
    return 2.0f*sigf(2.0f*x) - 1.0f;   // safe at +-inf
}
__device__ __forceinline__ void gload16(const ushort_t* g, char* l){
    __builtin_amdgcn_global_load_lds((const __attribute__((address_space(1))) void*)g,
                                     (__attribute__((address_space(3))) void*)l, 16, 0, 0);
}

// ---------- setup: W_out convert+pad; blocks<768 also Wih/Whh/biasg/h-init;
//            blocks<6400 also gather+convert one embedding row ----------
// grid exact: NPAD*DW/4/256 = 15104 blocks, 256 thr
__global__ void k_setup(const f4* __restrict__ s, ushort_t* __restrict__ d,
                        const f4* __restrict__ wih, const f4* __restrict__ whh,
                        ushort_t* __restrict__ dih, ushort_t* __restrict__ dhh,
                        const float* __restrict__ bi, const float* __restrict__ bh,
                        float* __restrict__ bg, float* __restrict__ hf,
                        ushort_t* __restrict__ hb,
                        const float* __restrict__ emb, const int* __restrict__ idx,
                        ushort_t* __restrict__ xb){
    int i = blockIdx.x*blockDim.x + threadIdx.x;     // < NPAD*DW/4
    uint2 o = make_uint2(0u, 0u);
    if (i < VOCAB*DW/4){
        f4 v = s[i];
        o.x = (unsigned)f2b(v[0]) | ((unsigned)f2b(v[1]) << 16);
        o.y = (unsigned)f2b(v[2]) | ((unsigned)f2b(v[3]) << 16);
    }
    *(uint2*)(d + (size_t)i*4) = o;
    if (i < G3*DW/4){
        f4 v = wih[i];
        unsigned lo = (unsigned)f2b(v[0]) | ((unsigned)f2b(v[1]) << 16);
        unsigned hi = (unsigned)f2b(v[2]) | ((unsigned)f2b(v[3]) << 16);
        *(uint2*)(dih + (size_t)i*4) = make_uint2(lo, hi);
        v = whh[i];
        lo = (unsigned)f2b(v[0]) | ((unsigned)f2b(v[1]) << 16);
        hi = (unsigned)f2b(v[2]) | ((unsigned)f2b(v[3]) << 16);
        *(uint2*)(dhh + (size_t)i*4) = make_uint2(lo, hi);
        if (i < G3) bg[i] = bi[i] + (i < 2*HDIM ? bh[i] : 0.0f);
        if (i < BB*HDIM){ hf[i] = 0.0f; hb[i] = 0; }
    }
    if (blockIdx.x < M_ROWS){
        int row = blockIdx.x;
        int v = idx[row];
        float2 w = ((const float2*)(emb + (size_t)v*DW))[threadIdx.x];   // DW/2 == 256 == blockDim
        ((unsigned*)(xb + (size_t)row*DW))[threadIdx.x] =
            (unsigned)f2b(w.x) | ((unsigned)f2b(w.y) << 16);
    }
}

// ---------- phase A: 128x128 BK=64 bf16 GEMM + bias, bf16 out (r11 loop + r8 epilogue) ----------
template<int NBLK>
__global__ __launch_bounds__(256, 4) void k_gemmA(const ushort_t* __restrict__ A,
        const ushort_t* __restrict__ Bw, const float* __restrict__ bias,
        ushort_t* __restrict__ Cout){
    __shared__ ushort_t As[128*64];
    __shared__ ushort_t Bs[128*64];
    const int nwg = NBLK * 50;
    const int q = nwg >> 3;
    int wgid = (blockIdx.x & 7)*q + (blockIdx.x >> 3);
    int band = wgid / (10*NBLK);
    int rr   = wgid % (10*NBLK);
    int nb = rr / 10;
    int mb = band*10 + (rr % 10);
    int n0 = nb*128, m0 = mb*128;

    int tid = threadIdx.x;
    int lane = tid & 63, wv = tid >> 6;
    int lo = lane & 15, hi = lane >> 4;
    int wr = wv >> 1, wc = wv & 1;
    f32x4 acc[4][4] = {};
    int srow = lane >> 3;
    int xslot = (lane & 7) ^ srow;
    const ushort_t* gA = A  + (size_t)(m0 + wv*32 + srow)*KDIM + xslot*8;
    const ushort_t* gB = Bw + (size_t)(n0 + wv*32 + srow)*KDIM + xslot*8;
    char* lA = (char*)As + (size_t)(wv*32)*128;
    char* lB = (char*)Bs + (size_t)(wv*32)*128;
    for (int kt = 0; kt < 8; ++kt){
        __syncthreads();
        int k0 = kt*64;
        #pragma unroll
        for (int c4 = 0; c4 < 4; ++c4){
            gload16(gA + (size_t)c4*8*KDIM + k0, lA + c4*8*128);
            gload16(gB + (size_t)c4*8*KDIM + k0, lB + c4*8*128);
        }
        __syncthreads();
        short8 av[4][2], bv[4][2];
        #pragma unroll
        for (int mi = 0; mi < 4; ++mi){
            int rrow = wr*64 + mi*16 + lo;
            #pragma unroll
            for (int ks = 0; ks < 2; ++ks)
                av[mi][ks] = *(const short8*)&As[rrow*64 + (((ks*4+hi) ^ (lo&7)))*8];
        }
        #pragma unroll
        for (int ni = 0; ni < 4; ++ni){
            int rrow = wc*64 + ni*16 + lo;
            #pragma unroll
            for (int ks = 0; ks < 2; ++ks)
                bv[ni][ks] = *(const short8*)&Bs[rrow*64 + (((ks*4+hi) ^ (lo&7)))*8];
        }
        #pragma unroll
        for (int mi = 0; mi < 4; ++mi)
            #pragma unroll
            for (int ni = 0; ni < 4; ++ni){
                acc[mi][ni] = __builtin_amdgcn_mfma_f32_16x16x32_bf16(av[mi][0], bv[ni][0], acc[mi][ni], 0, 0, 0);
                acc[mi][ni] = __builtin_amdgcn_mfma_f32_16x16x32_bf16(av[mi][1], bv[ni][1], acc[mi][ni], 0, 0, 0);
            }
    }
    #pragma unroll
    for (int ni = 0; ni < 4; ++ni){
        int n = n0 + wc*64 + ni*16 + lo;
        float bb = bias[n];
        #pragma unroll
        for (int mi = 0; mi < 4; ++mi){
            #pragma unroll
            for (int j = 0; j < 4; ++j){
                int m = m0 + wr*64 + mi*16 + hi*4 + j;
                Cout[(size_t)m*G3 + n] = f2b(acc[mi][ni][j] + bb);
            }
        }
    }
}

// ---------- phase C: 128x128 BK=64 bf16 GEMM + sumexp epilogue (r11/r13-verified: 230us) ----------
template<int NBLK>
__global__ __launch_bounds__(256, 4) void k_gemmC(const ushort_t* __restrict__ A,
        const ushort_t* __restrict__ Bw, const float* __restrict__ bo,
        float* __restrict__ psum){
    __shared__ ushort_t As[128*64];
    __shared__ ushort_t Bs[128*64];
    const int nwg = NBLK * 50;
    const int q = nwg >> 3;
    int wgid = (blockIdx.x & 7)*q + (blockIdx.x >> 3);
    int band = wgid / (10*NBLK);
    int rr   = wgid % (10*NBLK);
    int nb = rr / 10;
    int mb = band*10 + (rr % 10);
    int n0 = nb*128, m0 = mb*128;

    int tid = threadIdx.x;
    int lane = tid & 63, wv = tid >> 6;
    int lo = lane & 15, hi = lane >> 4;
    int wr = wv >> 1, wc = wv & 1;
    f32x4 acc[4][4] = {};
    int srow = lane >> 3;
    int xslot = (lane & 7) ^ srow;
    const ushort_t* gA = A  + (size_t)(m0 + wv*32 + srow)*KDIM + xslot*8;
    const ushort_t* gB = Bw + (size_t)(n0 + wv*32 + srow)*KDIM + xslot*8;
    char* lA = (char*)As + (size_t)(wv*32)*128;
    char* lB = (char*)Bs + (size_t)(wv*32)*128;
    for (int kt = 0; kt < 8; ++kt){
        __syncthreads();
        int k0 = kt*64;
        #pragma unroll
        for (int c4 = 0; c4 < 4; ++c4){
            gload16(gA + (size_t)c4*8*KDIM + k0, lA + c4*8*128);
            gload16(gB + (size_t)c4*8*KDIM + k0, lB + c4*8*128);
        }
        __syncthreads();
        short8 av[4][2], bv[4][2];
        #pragma unroll
        for (int mi = 0; mi < 4; ++mi){
            int rrow = wr*64 + mi*16 + lo;
            #pragma unroll
            for (int ks = 0; ks < 2; ++ks)
                av[mi][ks] = *(const short8*)&As[rrow*64 + (((ks*4+hi) ^ (lo&7)))*8];
        }
        #pragma unroll
        for (int ni = 0; ni < 4; ++ni){
            int rrow = wc*64 + ni*16 + lo;
            #pragma unroll
            for (int ks = 0; ks < 2; ++ks)
                bv[ni][ks] = *(const short8*)&Bs[rrow*64 + (((ks*4+hi) ^ (lo&7)))*8];
        }
        #pragma unroll
        for (int mi = 0; mi < 4; ++mi)
            #pragma unroll
            for (int ni = 0; ni < 4; ++ni){
                acc[mi][ni] = __builtin_amdgcn_mfma_f32_16x16x32_bf16(av[mi][0], bv[ni][0], acc[mi][ni], 0, 0, 0);
                acc[mi][ni] = __builtin_amdgcn_mfma_f32_16x16x32_bf16(av[mi][1], bv[ni][1], acc[mi][ni], 0, 0, 0);
            }
    }
    float bov[4];
    bool valid[4];
    #pragma unroll
    for (int ni = 0; ni < 4; ++ni){
        int col = n0 + wc*64 + ni*16 + lo;
        valid[ni] = (col < VOCAB);
        bov[ni] = valid[ni] ? bo[col] : 0.0f;
    }
    int tile = nb*2 + wc;
    #pragma unroll
    for (int mi = 0; mi < 4; ++mi){
        #pragma unroll
        for (int j = 0; j < 4; ++j){
            float s = 0.0f;
            #pragma unroll
            for (int ni = 0; ni < 4; ++ni)
                s += valid[ni] ? __expf(acc[mi][ni][j] + bov[ni]) : 0.0f;
            for (int d = 1; d < 16; d <<= 1) s += __shfl_xor(s, d, 64);
            if (lo == 0){
                int m = m0 + wr*64 + mi*16 + hi*4 + j;
                psum[(size_t)m*NT2 + tile] = s;
            }
        }
    }
}

// ---------- one GRU step: grid (32 ctiles, 8 btiles), block 64 (r7-verified ~3.8us/step) ----------
__global__ __launch_bounds__(64) void k_step(const ushort_t* __restrict__ hprev_b,
        const float* __restrict__ hprev_f, const ushort_t* __restrict__ Whh,
        const ushort_t* __restrict__ xg, const float* __restrict__ bh,
        float* __restrict__ hnext_f, ushort_t* __restrict__ hnext_b,
        ushort_t* __restrict__ outs, int t){
    int lane = threadIdx.x;
    int lo = lane & 15, hi = lane >> 4;
    int c16 = blockIdx.x * 16;   // h-col base
    int b0  = blockIdx.y * 16;   // batch base
    f32x4 acc[3] = {};
    const ushort_t* Arow = hprev_b + (size_t)(b0 + lo)*HDIM;
    #pragma unroll
    for (int kk = 0; kk < 16; ++kk){
        int k0 = kk*32 + hi*8;
        short8 a = *(const short8*)(Arow + k0);
        #pragma unroll
        for (int g = 0; g < 3; ++g){
            short8 b = *(const short8*)(Whh + (size_t)(g*HDIM + c16 + lo)*HDIM + k0);
            acc[g] = __builtin_amdgcn_mfma_f32_16x16x32_bf16(a, b, acc[g], 0, 0, 0);
        }
    }
    int c = c16 + lo;
    float bhn = bh[2*HDIM + c];
    const ushort_t* xgt = xg + (size_t)t*BB*G3;
    #pragma unroll
    for (int j = 0; j < 4; ++j){
        int bt = b0 + hi*4 + j;
        float xr = b2f(xgt[(size_t)bt*G3 + c]);
        float xz = b2f(xgt[(size_t)bt*G3 + HDIM + c]);
        float xn = b2f(xgt[(size_t)bt*G3 + 2*HDIM + c]);
        float r  = sigf(acc[0][j] + xr);
        float z  = sigf(acc[1][j] + xz);
        float n  = tanh_(xn + r*(acc[2][j] + bhn));
        float hold = hprev_f[(size_t)bt*HDIM + c];
        float hnew = (1.0f - z)*n + z*hold;
        hnext_f[(size_t)bt*HDIM + c] = hnew;
        ushort_t hb = f2b(hnew);
        hnext_b[(size_t)bt*HDIM + c] = hb;
        outs[((size_t)t*BB + bt)*HDIM + c] = hb;
    }
}

// ---------- fused: lse combine + nll per row (wave per row) ----------
__global__ __launch_bounds__(256) void k_loss(const ushort_t* __restrict__ outs,
        const ushort_t* __restrict__ Wo, const float* __restrict__ bo,
        const float* __restrict__ psum, const int* __restrict__ tgt,
        float* __restrict__ out){
    int lane = threadIdx.x & 63, wv = threadIdx.x >> 6;
    int row = blockIdx.x*4 + wv;
    int tg = tgt[row];
    const float* ps = psum + (size_t)row*NT2;
    float S = 0.0f;
    for (int t = lane; t < NT2; t += 64) S += ps[t];
    for (int d = 1; d < 64; d <<= 1) S += __shfl_xor(S, d, 64);
    float lse = __logf(S);
    const ushort_t* a = outs + (size_t)row*HDIM + lane*8;
    const ushort_t* w = Wo + (size_t)tg*DW + lane*8;
    float s = 0.0f;
    #pragma unroll
    for (int j = 0; j < 8; ++j) s += b2f(a[j]) * b2f(w[j]);
    for (int d = 1; d < 64; d <<= 1) s += __shfl_xor(s, d, 64);
    if (lane == 0){
        float logit = s + bo[tg];
        out[row] = (tg != 0) ? (lse - logit) : 0.0f;
    }
}

// ---------- obj = sum(loss)/max(count,1) ----------
__global__ __launch_bounds__(1024) void k_obj(const float* __restrict__ loss,
        const int* __restrict__ tgt, float* __restrict__ out){
    __shared__ float ss[1024];
    __shared__ int   sc[1024];
    float s = 0.0f; int c = 0;
    for (int i = threadIdx.x; i < M_ROWS; i += 1024){
        s += loss[i];
        c += (tgt[i] != 0) ? 1 : 0;
    }
    ss[threadIdx.x] = s; sc[threadIdx.x] = c;
    __syncthreads();
    for (int d = 512; d > 0; d >>= 1){
        if (threadIdx.x < (unsigned)d){ ss[threadIdx.x] += ss[threadIdx.x+d]; sc[threadIdx.x] += sc[threadIdx.x+d]; }
        __syncthreads();
    }
    if (threadIdx.x == 0) out[M_ROWS] = ss[0] / (float)(sc[0] > 0 ? sc[0] : 1);
}

extern "C" void kernel_launch(void* const* d_in, const int* in_sizes, int n_in,
                              void* d_out, int out_size, void* d_ws, size_t ws_size,
                              hipStream_t stream) {
    const int*   review_input  = (const int*)d_in[2];
    const int*   review_target = (const int*)d_in[3];
    const float* word_emb = (const float*)d_in[4];
    const float* W_ih = (const float*)d_in[5];
    const float* W_hh = (const float*)d_in[6];
    const float* b_ih = (const float*)d_in[7];
    const float* b_hh = (const float*)d_in[8];
    const float* W_out = (const float*)d_in[9];
    const float* b_out = (const float*)d_in[10];
    float* out = (float*)d_out;
    (void)n_in; (void)in_sizes; (void)out_size; (void)ws_size;

    char* ws = (char*)d_ws;
    size_t off = 0;
    auto alloc = [&](size_t bytes)->char*{
        char* p = ws + off;
        off = (off + bytes + 255) & ~(size_t)255;
        return p;
    };
    ushort_t* Wout_b = (ushort_t*)alloc((size_t)NPAD*DW*2);      // 30.9 MB (padded)
    ushort_t* Wih_b  = (ushort_t*)alloc((size_t)G3*DW*2);
    ushort_t* Whh_b  = (ushort_t*)alloc((size_t)G3*HDIM*2);
    ushort_t* outs_b = (ushort_t*)alloc((size_t)M_ROWS*HDIM*2);  // live through loss
    float*    biasg  = (float*)alloc((size_t)G3*4);
    float*    h_f    = (float*)alloc((size_t)2*BB*HDIM*4);
    ushort_t* h_b    = (ushort_t*)alloc((size_t)2*BB*HDIM*2);
    // xb + xg dead by phase C -> psum ([row][tile], 12.1 MB) aliases this span
    ushort_t* xb     = (ushort_t*)alloc((size_t)M_ROWS*DW*2);
    ushort_t* xg     = (ushort_t*)alloc((size_t)M_ROWS*G3*2);
    float*    psum   = (float*)xb;

    // setup: 1 launch (W_out cvt+pad, Wih/Whh cvt, biasg, h-init, embed-gather)
    k_setup<<<NPAD*DW/4/256, 256, 0, stream>>>((const f4*)W_out, Wout_b,
                                               (const f4*)W_ih, (const f4*)W_hh,
                                               Wih_b, Whh_b, b_ih, b_hh, biasg, h_f, h_b,
                                               word_emb, review_input, xb);

    // phase A: xg = x @ W_ih^T + biasg   (12 nb x 50 mb = 600 WGs, BK=64 body)
    k_gemmA<12><<<600, 256, 0, stream>>>(xb, Wih_b, biasg, xg);

    // phase B: 50 sequential steps, double-buffered h (dependent launches = the
    // measured-cheapest scan mechanism on CDNA4; r5/r10/r12 alternatives 5-25x worse;
    // block-64 single-wave step measured fastest: r7 ~3.8us/step)
    for (int t = 0; t < TT; ++t){
        int cur = t & 1, nxt = cur ^ 1;
        k_step<<<dim3(HDIM/16, BB/16), 64, 0, stream>>>(h_b + (size_t)cur*BB*HDIM,
                                       h_f + (size_t)cur*BB*HDIM,
                                       Whh_b, xg, b_hh,
                                       h_f + (size_t)nxt*BB*HDIM,
                                       h_b + (size_t)nxt*BB*HDIM,
                                       outs_b, t);
    }

    // phase C: fused logits + sumexp partials (236 nb x 50 mb = 11800 WGs), loss, obj
    k_gemmC<236><<<11800, 256, 0, stream>>>(outs_b, Wout_b, b_out, psum);
    k_loss<<<M_ROWS/4, 256, 0, stream>>>(outs_b, Wout_b, b_out, psum, review_target, out);
    k_obj<<<1, 1024, 0, stream>>>(out, review_target, out);
}